// Round 3
// baseline (2073.566 us; speedup 1.0000x reference)
//
#include <hip/hip_runtime.h>

#define CS 2048
#define CT 64
#define CHL 128   // steps per chunk
#define NCH 16    // chunks per sequence

typedef float f32x16 __attribute__((ext_vector_type(16)));
typedef short short8v __attribute__((ext_vector_type(8)));

static __device__ __forceinline__ float fexp(float x) {
  return __builtin_amdgcn_exp2f(x * 1.4426950408889634f);
}
static __device__ __forceinline__ float flog(float x) {
  return 0.6931471805599453f * __builtin_amdgcn_logf(x);
}
static __device__ __forceinline__ unsigned cvt_pk_bf16(float lo, float hi) {
  unsigned r;
  asm("v_cvt_pk_bf16_f32 %0, %1, %2" : "=v"(r) : "v"(lo), "v"(hi));
  return r;
}
// v_permlane32_swap_b32: newx = [x.lo32 | y.lo32], newy = [x.hi32 | y.hi32]
static __device__ __forceinline__ void pl32_swap(unsigned& x, unsigned& y) {
  asm("v_permlane32_swap_b32 %0, %1" : "+v"(x), "+v"(y));
}

static __device__ __forceinline__ float wave_max_f(float v) {
#pragma unroll
  for (int off = 32; off > 0; off >>= 1) v = fmaxf(v, __shfl_xor(v, off, 64));
  return v;
}
static __device__ __forceinline__ float wave_sum_f(float v) {
#pragma unroll
  for (int off = 32; off > 0; off >>= 1) v += __shfl_xor(v, off, 64);
  return v;
}
static __device__ __forceinline__ int wave_sum_i(int v) {
#pragma unroll
  for (int off = 32; off > 0; off >>= 1) v += __shfl_xor(v, off, 64);
  return v;
}

static __device__ __forceinline__ int seq_len(const unsigned char* mask_u8, int b,
                                              bool mask_is_i32, int lane) {
  if (!mask_is_i32) {
    const uint4* m4 = (const uint4*)(mask_u8 + (size_t)b * CS);
    unsigned ls = 0;
#pragma unroll
    for (int k = 0; k < CS / (16 * 64); ++k) {
      uint4 w = m4[lane + 64 * k];
      ls += ((w.x * 0x01010101u) >> 24) + ((w.y * 0x01010101u) >> 24) +
            ((w.z * 0x01010101u) >> 24) + ((w.w * 0x01010101u) >> 24);
    }
    return wave_sum_i((int)ls);
  } else {
    const int* mi = (const int*)mask_u8 + (size_t)b * CS;
    int ls = 0;
    for (int s = lane; s < CS; s += 64) ls += mi[s];
    return wave_sum_i(ls);
  }
}

// ---------------- Phase A: per-(seq,chunk) transfer matrix via MFMA ----------------
__global__ __launch_bounds__(64, 2) void crf_chunkA(
    const float* __restrict__ feats, const float* __restrict__ trans,
    const unsigned char* __restrict__ mask_u8,
    unsigned* __restrict__ qws, float* __restrict__ scalews) {
  const int blk = blockIdx.x;
  const int b = blk >> 4;   // NCH == 16
  const int c = blk & 15;
  const int lane = threadIdx.x;
  const int l31 = lane & 31;
  const int h = lane >> 5;

  __shared__ float efb[2][CT];

  const unsigned mw0 = *(const unsigned*)mask_u8;
  const bool mask_is_i32 = (mw0 <= 1u);
  const int len = seq_len(mask_u8, b, mask_is_i32, lane);

  const int lo = 1 + c * CHL;
  const int hi = min(lo + CHL, len);

  typedef union { unsigned u[4]; short8v s8; } frag;

  // A = E^T (constant): lane elem e of Af[rt][kt] = exp(trans[16kt+8h+e][32rt+l31])
  frag Af[2][4];
#pragma unroll
  for (int rt = 0; rt < 2; ++rt)
#pragma unroll
    for (int kt = 0; kt < 4; ++kt) {
      float ev[8];
#pragma unroll
      for (int e = 0; e < 8; ++e)
        ev[e] = fexp(trans[(16 * kt + 8 * h + e) * CT + 32 * rt + l31]);
#pragma unroll
      for (int p = 0; p < 4; ++p)
        Af[rt][kt].u[p] = cvt_pk_bf16(ev[2 * p], ev[2 * p + 1]);
    }

  // B = Identity (bf16)
  frag Bf[4][2];
#pragma unroll
  for (int kt = 0; kt < 4; ++kt)
#pragma unroll
    for (int ct = 0; ct < 2; ++ct) {
#pragma unroll
      for (int p = 0; p < 4; ++p) Bf[kt][ct].u[p] = 0u;
      int d = 32 * ct + l31 - 16 * kt - 8 * h;
      if (d >= 0 && d < 8) Bf[kt][ct].u[d >> 1] = 0x3F80u << (16 * (d & 1));
    }

  float Mc = 0.0f;

  if (lo < hi) {
    const float* fb = feats + (size_t)b * CS * CT;
    efb[lo & 1][lane] = fexp(fb[(size_t)lo * CT + lane]);
    int p1 = min(lo + 1, CS - 1), p2 = min(lo + 2, CS - 1);
    float fv1 = fb[(size_t)p1 * CT + lane];
    float fv2 = fb[(size_t)p2 * CT + lane];

    for (int s = lo; s < hi; ++s) {
      float fv = fv1;
      fv1 = fv2;
      int p3 = min(s + 3, CS - 1);
      fv2 = fb[(size_t)p3 * CT + lane];
      if (s + 1 < hi) efb[(s + 1) & 1][lane] = fexp(fv);

      // acc = E^T * Q
      f32x16 acc[2][2];
#pragma unroll
      for (int rt = 0; rt < 2; ++rt)
#pragma unroll
        for (int ct = 0; ct < 2; ++ct) {
          f32x16 a;
#pragma unroll
          for (int g = 0; g < 16; ++g) a[g] = 0.0f;
#pragma unroll
          for (int kt = 0; kt < 4; ++kt)
            a = __builtin_amdgcn_mfma_f32_32x32x16_bf16(Af[rt][kt].s8, Bf[kt][ct].s8, a, 0, 0, 0);
          acc[rt][ct] = a;
        }

      // every 4 steps: FULL-max rescale (all 64 entries/lane + full 64-lane reduce).
      // With true-max normalization, 4-step growth < e^46 << bf16 max e^88 -> no Inf.
      float pinv = 1.0f;
      if (((s - lo) & 3) == 3) {
        float m = acc[0][0][0];
#pragma unroll
        for (int rt = 0; rt < 2; ++rt)
#pragma unroll
          for (int ct = 0; ct < 2; ++ct)
#pragma unroll
            for (int g = 0; g < 16; ++g) m = fmaxf(m, acc[rt][ct][g]);
        m = wave_max_f(m);
        Mc += flog(m);
        pinv = __builtin_amdgcn_rcpf(m);
      }

      // B_next = bf16(diag(ef_s*pinv) * acc), repack C-layout -> B-layout
#pragma unroll
      for (int rt = 0; rt < 2; ++rt)
#pragma unroll
        for (int q = 0; q < 2; ++q) {
          const int kt = 2 * rt + q;
          // sc8[j] = ef[32rt+16q+8*(j>>2)+4h+(j&3)] * pinv  (shared across ct)
          float sc8[8];
          {
            float4 t0 = *(const float4*)&efb[s & 1][32 * rt + 16 * q + 4 * h];
            float4 t1 = *(const float4*)&efb[s & 1][32 * rt + 16 * q + 8 + 4 * h];
            sc8[0] = t0.x * pinv; sc8[1] = t0.y * pinv;
            sc8[2] = t0.z * pinv; sc8[3] = t0.w * pinv;
            sc8[4] = t1.x * pinv; sc8[5] = t1.y * pinv;
            sc8[6] = t1.z * pinv; sc8[7] = t1.w * pinv;
          }
#pragma unroll
          for (int ct = 0; ct < 2; ++ct) {
            float v[8];
#pragma unroll
            for (int j = 0; j < 8; ++j) v[j] = acc[rt][ct][8 * q + j] * sc8[j];
            unsigned p01 = cvt_pk_bf16(v[0], v[1]);
            unsigned p23 = cvt_pk_bf16(v[2], v[3]);
            unsigned p45 = cvt_pk_bf16(v[4], v[5]);
            unsigned p67 = cvt_pk_bf16(v[6], v[7]);
            pl32_swap(p01, p45);
            pl32_swap(p23, p67);
            Bf[kt][ct].u[0] = p01;
            Bf[kt][ct].u[1] = p23;
            Bf[kt][ct].u[2] = p45;
            Bf[kt][ct].u[3] = p67;
          }
        }
    }
  }

  unsigned* qd = qws + (size_t)blk * 2048;
#pragma unroll
  for (int kt = 0; kt < 4; ++kt)
#pragma unroll
    for (int ct = 0; ct < 2; ++ct)
#pragma unroll
      for (int p = 0; p < 4; ++p)
        qd[((kt * 2 + ct) * 4 + p) * 64 + lane] = Bf[kt][ct].u[p];
  if (lane == 0) scalews[blk] = Mc;
}

// ---------------- Phase B: stitch chunks + gold path (+ sequential fallback) ------
__global__ __launch_bounds__(64, 1) void crf_phaseB(
    const float* __restrict__ feats, const float* __restrict__ trans,
    const float* __restrict__ startt, const float* __restrict__ endt,
    const int* __restrict__ tags_i32, const unsigned char* __restrict__ mask_u8,
    const unsigned* __restrict__ qws, const float* __restrict__ scalews,
    float* __restrict__ out) {
  const int b = blockIdx.x;
  const int lane = threadIdx.x;
  const int l31 = lane & 31;
  const int h = lane >> 5;
  __shared__ float a_sh[CT];
  __shared__ unsigned short qlds[CT * 66];

  int oddv = (lane < 32) ? tags_i32[2 * lane + 1] : 0;
  const bool tags64 = (__ballot(oddv != 0) == 0ull);
  const unsigned mw0 = *(const unsigned*)mask_u8;
  const bool mask_is_i32 = (mw0 <= 1u);
  const int len = seq_len(mask_u8, b, mask_is_i32, lane);

  const float* frow0 = feats + (size_t)b * CS * CT;

  auto tg = [&](int s) -> int {
    size_t idx = (size_t)b * CS + s;
    return tags64 ? tags_i32[2 * idx] : tags_i32[idx];
  };
  float g = 0.f;
  for (int s = lane; s < len; s += 64) {
    int tc = tg(s);
    g += frow0[(size_t)s * CT + tc];
    if (s > 0) g += trans[tg(s - 1) * CT + tc];
  }
  g = wave_sum_f(g);
  const float gold = g + startt[tg(0)] + endt[tg(len - 1)];

  float alpha0 = startt[lane] + frow0[lane];
  float m0 = wave_max_f(alpha0);
  float M = m0;
  float a = fexp(alpha0 - m0);
  a_sh[lane] = a;

  for (int c = 0; c < NCH; ++c) {
    const unsigned* qd = qws + (size_t)(b * NCH + c) * 2048;
    unsigned w[32];
#pragma unroll
    for (int i = 0; i < 32; ++i) w[i] = qd[i * 64 + lane];
#pragma unroll
    for (int i = 0; i < 32; ++i) {
      int kt = i >> 3, ct = (i >> 2) & 1, p = i & 3;
      int row = 16 * kt + 8 * h + 2 * p;
      int col = 32 * ct + l31;
      *(unsigned*)&qlds[col * 66 + row] = w[i];
    }
    float v = 0.0f;
#pragma unroll
    for (int i = 0; i < CT; ++i) {
      float qf = __uint_as_float(((unsigned)qlds[i * 66 + lane]) << 16);
      v = fmaf(qf, a_sh[i], v);
    }
    M += scalews[b * NCH + c];
    float mx = wave_max_f(v);
    a = v * __builtin_amdgcn_rcpf(mx);
    M += flog(mx);
    a_sh[lane] = a;
  }

  float se = wave_sum_f(a * fexp(endt[lane]));
  float fwd = M + flog(se);

  // ---- safety net: if fast path produced non-finite, recompute sequentially ----
  if (!isfinite(fwd)) {
    float Ecol[CT];
#pragma unroll
    for (int i = 0; i < CT; ++i) Ecol[i] = fexp(trans[i * CT + lane]);
    float alpha0b = startt[lane] + frow0[lane];
    float m0b = wave_max_f(alpha0b);
    float Mb = m0b;
    float aj = fexp(alpha0b - m0b);
    a_sh[lane] = aj;
    float fcur = frow0[CT + lane];
    float fnext = frow0[2 * CT + lane];
    for (int s = 1; s < len; ++s) {
      float ef = fexp(fcur);
      fcur = fnext;
      int sp = s + 2;
      sp = sp < CS ? sp : CS - 1;
      fnext = frow0[(size_t)sp * CT + lane];
      float acc0 = 0.f, acc1 = 0.f, acc2 = 0.f, acc3 = 0.f;
#pragma unroll
      for (int i = 0; i < CT; i += 4) {
        float4 av = *(const float4*)(&a_sh[i]);
        acc0 = fmaf(av.x, Ecol[i + 0], acc0);
        acc1 = fmaf(av.y, Ecol[i + 1], acc1);
        acc2 = fmaf(av.z, Ecol[i + 2], acc2);
        acc3 = fmaf(av.w, Ecol[i + 3], acc3);
      }
      float v = ((acc0 + acc1) + (acc2 + acc3)) * ef;
      if ((s & 3) == 0) {
        float cmx = wave_max_f(v);
        Mb += flog(cmx);
        v = v * __builtin_amdgcn_rcpf(cmx);
      }
      aj = v;
      a_sh[lane] = aj;
    }
    float se2 = wave_sum_f(aj * fexp(endt[lane]));
    fwd = Mb + flog(se2);
  }

  if (lane == 0) atomicAdd(out, fwd - gold);
}

// ---------------- Fallback: sequential kernel (ws too small) ----------------
__global__ __launch_bounds__(64, 1) void crf_nll_kernel(
    const float* __restrict__ feats, const float* __restrict__ trans,
    const float* __restrict__ startt, const float* __restrict__ endt,
    const int* __restrict__ tags_i32, const unsigned char* __restrict__ mask_u8,
    float* __restrict__ out) {
  const int b = blockIdx.x;
  const int lane = threadIdx.x;
  __shared__ float a_sh[CT];

  int oddv = (lane < 32) ? tags_i32[2 * lane + 1] : 0;
  const bool tags64 = (__ballot(oddv != 0) == 0ull);
  const unsigned mw0 = *(const unsigned*)mask_u8;
  const bool mask_is_i32 = (mw0 <= 1u);
  const int len = seq_len(mask_u8, b, mask_is_i32, lane);

  const float* frow0 = feats + (size_t)b * CS * CT;
  auto tg = [&](int s) -> int {
    size_t idx = (size_t)b * CS + s;
    return tags64 ? tags_i32[2 * idx] : tags_i32[idx];
  };
  float g = 0.f;
  for (int s = lane; s < len; s += 64) {
    int tc = tg(s);
    g += frow0[(size_t)s * CT + tc];
    if (s > 0) g += trans[tg(s - 1) * CT + tc];
  }
  g = wave_sum_f(g);
  const float gold = g + startt[tg(0)] + endt[tg(len - 1)];

  float Ecol[CT];
#pragma unroll
  for (int i = 0; i < CT; ++i) Ecol[i] = fexp(trans[i * CT + lane]);

  float alpha0 = startt[lane] + frow0[lane];
  float m0 = wave_max_f(alpha0);
  float M = m0;
  float aj = fexp(alpha0 - m0);
  a_sh[lane] = aj;

  float fcur = frow0[CT + lane];
  float fnext = frow0[2 * CT + lane];
  for (int s = 1; s < len; ++s) {
    float ef = fexp(fcur);
    fcur = fnext;
    int sp = s + 2;
    sp = sp < CS ? sp : CS - 1;
    fnext = frow0[(size_t)sp * CT + lane];

    float acc0 = 0.f, acc1 = 0.f, acc2 = 0.f, acc3 = 0.f;
#pragma unroll
    for (int i = 0; i < CT; i += 4) {
      float4 av = *(const float4*)(&a_sh[i]);
      acc0 = fmaf(av.x, Ecol[i + 0], acc0);
      acc1 = fmaf(av.y, Ecol[i + 1], acc1);
      acc2 = fmaf(av.z, Ecol[i + 2], acc2);
      acc3 = fmaf(av.w, Ecol[i + 3], acc3);
    }
    float v = ((acc0 + acc1) + (acc2 + acc3)) * ef;
    if ((s & 3) == 0) {
      float cmx = wave_max_f(v);
      M += flog(cmx);
      v = v * __builtin_amdgcn_rcpf(cmx);
    }
    aj = v;
    a_sh[lane] = aj;
  }
  float se = wave_sum_f(aj * fexp(endt[lane]));
  float fwd = M + flog(se);
  if (lane == 0) atomicAdd(out, fwd - gold);
}

extern "C" void kernel_launch(void* const* d_in, const int* in_sizes, int n_in,
                              void* d_out, int out_size, void* d_ws, size_t ws_size,
                              hipStream_t stream) {
  const float* feats = (const float*)d_in[0];
  const float* trans = (const float*)d_in[1];
  const float* startt = (const float*)d_in[2];
  const float* endt = (const float*)d_in[3];
  const int* tags = (const int*)d_in[4];
  const unsigned char* mask = (const unsigned char*)d_in[5];
  float* out = (float*)d_out;

  int Bn = in_sizes[5] / CS;
  size_t qbytes = (size_t)Bn * NCH * 2048 * 4;
  size_t need = qbytes + (size_t)Bn * NCH * 4;

  hipMemsetAsync(out, 0, sizeof(float) * out_size, stream);
  if (ws_size >= need) {
    unsigned* qws = (unsigned*)d_ws;
    float* scalews = (float*)((char*)d_ws + qbytes);
    crf_chunkA<<<Bn * NCH, 64, 0, stream>>>(feats, trans, mask, qws, scalews);
    crf_phaseB<<<Bn, 64, 0, stream>>>(feats, trans, startt, endt, tags, mask, qws, scalews, out);
  } else {
    crf_nll_kernel<<<Bn, 64, 0, stream>>>(feats, trans, startt, endt, tags, mask, out);
  }
}

// Round 4
// 480.149 us; speedup vs baseline: 4.3186x; 4.3186x over previous
//
#include <hip/hip_runtime.h>

#define CS 2048
#define CT 64
#define CHL 128   // steps per chunk
#define NCH 16    // chunks per sequence
#define QST 72    // LDS row stride (u16) — keeps ds_read_b128 16B-aligned, breaks pow2 banks

typedef float f32x16 __attribute__((ext_vector_type(16)));
typedef short short8v __attribute__((ext_vector_type(8)));

static __device__ __forceinline__ float fexp(float x) {
  return __builtin_amdgcn_exp2f(x * 1.4426950408889634f);
}
static __device__ __forceinline__ float flog(float x) {
  return 0.6931471805599453f * __builtin_amdgcn_logf(x);
}
static __device__ __forceinline__ unsigned cvt_pk_bf16(float lo, float hi) {
  unsigned r;
  asm("v_cvt_pk_bf16_f32 %0, %1, %2" : "=v"(r) : "v"(lo), "v"(hi));
  return r;
}
static __device__ __forceinline__ float bf16_to_f(unsigned short u) {
  return __uint_as_float(((unsigned)u) << 16);
}

static __device__ __forceinline__ float wave_max_f(float v) {
#pragma unroll
  for (int off = 32; off > 0; off >>= 1) v = fmaxf(v, __shfl_xor(v, off, 64));
  return v;
}
static __device__ __forceinline__ float wave_sum_f(float v) {
#pragma unroll
  for (int off = 32; off > 0; off >>= 1) v += __shfl_xor(v, off, 64);
  return v;
}
static __device__ __forceinline__ int wave_sum_i(int v) {
#pragma unroll
  for (int off = 32; off > 0; off >>= 1) v += __shfl_xor(v, off, 64);
  return v;
}

static __device__ __forceinline__ int seq_len(const unsigned char* mask_u8, int b,
                                              bool mask_is_i32, int lane) {
  if (!mask_is_i32) {
    const uint4* m4 = (const uint4*)(mask_u8 + (size_t)b * CS);
    unsigned ls = 0;
#pragma unroll
    for (int k = 0; k < CS / (16 * 64); ++k) {
      uint4 w = m4[lane + 64 * k];
      ls += ((w.x * 0x01010101u) >> 24) + ((w.y * 0x01010101u) >> 24) +
            ((w.z * 0x01010101u) >> 24) + ((w.w * 0x01010101u) >> 24);
    }
    return wave_sum_i((int)ls);
  } else {
    const int* mi = (const int*)mask_u8 + (size_t)b * CS;
    int ls = 0;
    for (int s = lane; s < CS; s += 64) ls += mi[s];
    return wave_sum_i(ls);
  }
}

// ---------------- Phase A: per-(seq,chunk) transfer matrix via MFMA ----------------
// Q kept in LDS as [col][row] u16 (bf16), stride QST. B-operand fragments are
// direct ds_read_b128; C->B re-layout is plain scaled bf16 ds_write_b64s.
__global__ __launch_bounds__(64, 2) void crf_chunkA(
    const float* __restrict__ feats, const float* __restrict__ trans,
    const unsigned char* __restrict__ mask_u8,
    unsigned short* __restrict__ qws, float* __restrict__ scalews) {
  const int blk = blockIdx.x;
  const int b = blk >> 4;   // NCH == 16
  const int c = blk & 15;
  const int lane = threadIdx.x;
  const int l31 = lane & 31;
  const int h = lane >> 5;

  __shared__ float efb[2][CT];
  __shared__ unsigned short qsm[CT * QST];

  const unsigned mw0 = *(const unsigned*)mask_u8;
  const bool mask_is_i32 = (mw0 <= 1u);
  const int len = seq_len(mask_u8, b, mask_is_i32, lane);

  const int lo = 1 + c * CHL;
  const int hi = min(lo + CHL, len);

  // A = E^T (constant): lane elem e of Af[rt][kt] = exp(trans[16kt+8h+e][32rt+l31])
  short8v Af[2][4];
#pragma unroll
  for (int rt = 0; rt < 2; ++rt)
#pragma unroll
    for (int kt = 0; kt < 4; ++kt) {
      short8v av;
#pragma unroll
      for (int e = 0; e < 8; ++e) {
        float ev = fexp(trans[(16 * kt + 8 * h + e) * CT + 32 * rt + l31]);
        unsigned w = cvt_pk_bf16(ev, ev);
        av[e] = (short)(w & 0xFFFF);
      }
      Af[rt][kt] = av;
    }

  // Q0 = identity in LDS (zero all incl. pad, then diagonal)
#pragma unroll
  for (int c8 = 0; c8 < 9; ++c8)
    *(uint4*)&qsm[lane * QST + 8 * c8] = make_uint4(0u, 0u, 0u, 0u);
  qsm[lane * QST + lane] = 0x3F80;

  float Mc = 0.0f;

  if (lo < hi) {
    const float* fb = feats + (size_t)b * CS * CT;
    efb[lo & 1][lane] = fexp(fb[(size_t)lo * CT + lane]);
    int p1 = min(lo + 1, CS - 1), p2 = min(lo + 2, CS - 1);
    float fv1 = fb[(size_t)p1 * CT + lane];
    float fv2 = fb[(size_t)p2 * CT + lane];

    for (int s = lo; s < hi; ++s) {
      float fv = fv1;
      fv1 = fv2;
      int p3 = min(s + 3, CS - 1);
      fv2 = fb[(size_t)p3 * CT + lane];
      if (s + 1 < hi) efb[(s + 1) & 1][lane] = fexp(fv);

      // B fragments straight from LDS (16B-aligned: (32ct+l31)*72 + 16kt + 8h)
      short8v bq[4][2];
#pragma unroll
      for (int kt = 0; kt < 4; ++kt)
#pragma unroll
        for (int ct = 0; ct < 2; ++ct)
          bq[kt][ct] = *(const short8v*)&qsm[(32 * ct + l31) * QST + 16 * kt + 8 * h];

      // acc = E^T * Q
      f32x16 acc[2][2];
#pragma unroll
      for (int rt = 0; rt < 2; ++rt)
#pragma unroll
        for (int ct = 0; ct < 2; ++ct) {
          f32x16 a;
#pragma unroll
          for (int g = 0; g < 16; ++g) a[g] = 0.0f;
#pragma unroll
          for (int kt = 0; kt < 4; ++kt)
            a = __builtin_amdgcn_mfma_f32_32x32x16_bf16(Af[rt][kt], bq[kt][ct], a, 0, 0, 0);
          acc[rt][ct] = a;
        }

      // every 4 steps: FULL-max rescale (bounds all values; no overflow possible)
      float pinv = 1.0f;
      if (((s - lo) & 3) == 3) {
        float m = acc[0][0][0];
#pragma unroll
        for (int rt = 0; rt < 2; ++rt)
#pragma unroll
          for (int ct = 0; ct < 2; ++ct)
#pragma unroll
            for (int g = 0; g < 16; ++g) m = fmaxf(m, acc[rt][ct][g]);
        m = wave_max_f(m);
        Mc += flog(m);
        pinv = __builtin_amdgcn_rcpf(m);
      }

      // Q_next = bf16(diag(ef_s * pinv) * acc) written back to LDS [col][row]
      const float* ef = efb[s & 1];
#pragma unroll
      for (int rt = 0; rt < 2; ++rt)
#pragma unroll
        for (int q = 0; q < 2; ++q) {
          float4 e0 = *(const float4*)&ef[32 * rt + 16 * q + 4 * h];      // rows jb+0..3
          float4 e1 = *(const float4*)&ef[32 * rt + 16 * q + 8 + 4 * h];  // rows jb+8..11
          e0.x *= pinv; e0.y *= pinv; e0.z *= pinv; e0.w *= pinv;
          e1.x *= pinv; e1.y *= pinv; e1.z *= pinv; e1.w *= pinv;
          const int jb = 32 * rt + 16 * q + 4 * h;
#pragma unroll
          for (int ct = 0; ct < 2; ++ct) {
            const int base = 8 * q;
            unsigned w0 = cvt_pk_bf16(acc[rt][ct][base + 0] * e0.x, acc[rt][ct][base + 1] * e0.y);
            unsigned w1 = cvt_pk_bf16(acc[rt][ct][base + 2] * e0.z, acc[rt][ct][base + 3] * e0.w);
            unsigned w2 = cvt_pk_bf16(acc[rt][ct][base + 4] * e1.x, acc[rt][ct][base + 5] * e1.y);
            unsigned w3 = cvt_pk_bf16(acc[rt][ct][base + 6] * e1.z, acc[rt][ct][base + 7] * e1.w);
            const int col = 32 * ct + l31;
            *(uint2*)&qsm[col * QST + jb] = make_uint2(w0, w1);       // rows jb..jb+3
            *(uint2*)&qsm[col * QST + jb + 8] = make_uint2(w2, w3);   // rows jb+8..jb+11
          }
        }
    }
  }

  // store Q as plain [col][row] u16 matrix (64x64), coalesced-ish 16B chunks
  unsigned short* qd16 = qws + (size_t)blk * 4096;
#pragma unroll
  for (int c8 = 0; c8 < 8; ++c8) {
    uint4 w = *(const uint4*)&qsm[lane * QST + 8 * c8];
    *(uint4*)&qd16[lane * 64 + 8 * c8] = w;
  }
  if (lane == 0) scalews[blk] = Mc;
}

// ---------------- Phase B: stitch chunks + gold path (+ sequential fallback) ------
__global__ __launch_bounds__(64, 1) void crf_phaseB(
    const float* __restrict__ feats, const float* __restrict__ trans,
    const float* __restrict__ startt, const float* __restrict__ endt,
    const int* __restrict__ tags_i32, const unsigned char* __restrict__ mask_u8,
    const unsigned short* __restrict__ qws, const float* __restrict__ scalews,
    float* __restrict__ out) {
  const int b = blockIdx.x;
  const int lane = threadIdx.x;
  __shared__ float a_sh[CT];

  int oddv = (lane < 32) ? tags_i32[2 * lane + 1] : 0;
  const bool tags64 = (__ballot(oddv != 0) == 0ull);
  const unsigned mw0 = *(const unsigned*)mask_u8;
  const bool mask_is_i32 = (mw0 <= 1u);
  const int len = seq_len(mask_u8, b, mask_is_i32, lane);

  const float* frow0 = feats + (size_t)b * CS * CT;

  auto tg = [&](int s) -> int {
    size_t idx = (size_t)b * CS + s;
    return tags64 ? tags_i32[2 * idx] : tags_i32[idx];
  };
  float g = 0.f;
  for (int s = lane; s < len; s += 64) {
    int tc = tg(s);
    g += frow0[(size_t)s * CT + tc];
    if (s > 0) g += trans[tg(s - 1) * CT + tc];
  }
  g = wave_sum_f(g);
  const float gold = g + startt[tg(0)] + endt[tg(len - 1)];

  float alpha0 = startt[lane] + frow0[lane];
  float m0 = wave_max_f(alpha0);
  float M = m0;
  float a = fexp(alpha0 - m0);
  a_sh[lane] = a;

  for (int c = 0; c < NCH; ++c) {
    const unsigned short* q16 = qws + (size_t)(b * NCH + c) * 4096;
    // v[lane=j] = sum_i Q[row=j][col=i] * a[i]; Q stored [col][row] -> q16[i*64+j]
    float v = 0.0f;
#pragma unroll
    for (int i = 0; i < CT; i += 4) {
      float4 a4 = *(const float4*)&a_sh[i];
      v = fmaf(bf16_to_f(q16[(i + 0) * 64 + lane]), a4.x, v);
      v = fmaf(bf16_to_f(q16[(i + 1) * 64 + lane]), a4.y, v);
      v = fmaf(bf16_to_f(q16[(i + 2) * 64 + lane]), a4.z, v);
      v = fmaf(bf16_to_f(q16[(i + 3) * 64 + lane]), a4.w, v);
    }
    M += scalews[b * NCH + c];
    float mx = wave_max_f(v);
    a = v * __builtin_amdgcn_rcpf(mx);
    M += flog(mx);
    a_sh[lane] = a;
  }

  float se = wave_sum_f(a * fexp(endt[lane]));
  float fwd = M + flog(se);

  // ---- safety net: if fast path produced non-finite, recompute sequentially ----
  if (!isfinite(fwd)) {
    float Ecol[CT];
#pragma unroll
    for (int i = 0; i < CT; ++i) Ecol[i] = fexp(trans[i * CT + lane]);
    float alpha0b = startt[lane] + frow0[lane];
    float m0b = wave_max_f(alpha0b);
    float Mb = m0b;
    float aj = fexp(alpha0b - m0b);
    a_sh[lane] = aj;
    float fcur = frow0[CT + lane];
    float fnext = frow0[2 * CT + lane];
    for (int s = 1; s < len; ++s) {
      float ef = fexp(fcur);
      fcur = fnext;
      int sp = s + 2;
      sp = sp < CS ? sp : CS - 1;
      fnext = frow0[(size_t)sp * CT + lane];
      float acc0 = 0.f, acc1 = 0.f, acc2 = 0.f, acc3 = 0.f;
#pragma unroll
      for (int i = 0; i < CT; i += 4) {
        float4 av = *(const float4*)(&a_sh[i]);
        acc0 = fmaf(av.x, Ecol[i + 0], acc0);
        acc1 = fmaf(av.y, Ecol[i + 1], acc1);
        acc2 = fmaf(av.z, Ecol[i + 2], acc2);
        acc3 = fmaf(av.w, Ecol[i + 3], acc3);
      }
      float v = ((acc0 + acc1) + (acc2 + acc3)) * ef;
      if ((s & 3) == 0) {
        float cmx = wave_max_f(v);
        Mb += flog(cmx);
        v = v * __builtin_amdgcn_rcpf(cmx);
      }
      aj = v;
      a_sh[lane] = aj;
    }
    float se2 = wave_sum_f(aj * fexp(endt[lane]));
    fwd = Mb + flog(se2);
  }

  if (lane == 0) atomicAdd(out, fwd - gold);
}

// ---------------- Fallback: sequential kernel (ws too small) ----------------
__global__ __launch_bounds__(64, 1) void crf_nll_kernel(
    const float* __restrict__ feats, const float* __restrict__ trans,
    const float* __restrict__ startt, const float* __restrict__ endt,
    const int* __restrict__ tags_i32, const unsigned char* __restrict__ mask_u8,
    float* __restrict__ out) {
  const int b = blockIdx.x;
  const int lane = threadIdx.x;
  __shared__ float a_sh[CT];

  int oddv = (lane < 32) ? tags_i32[2 * lane + 1] : 0;
  const bool tags64 = (__ballot(oddv != 0) == 0ull);
  const unsigned mw0 = *(const unsigned*)mask_u8;
  const bool mask_is_i32 = (mw0 <= 1u);
  const int len = seq_len(mask_u8, b, mask_is_i32, lane);

  const float* frow0 = feats + (size_t)b * CS * CT;
  auto tg = [&](int s) -> int {
    size_t idx = (size_t)b * CS + s;
    return tags64 ? tags_i32[2 * idx] : tags_i32[idx];
  };
  float g = 0.f;
  for (int s = lane; s < len; s += 64) {
    int tc = tg(s);
    g += frow0[(size_t)s * CT + tc];
    if (s > 0) g += trans[tg(s - 1) * CT + tc];
  }
  g = wave_sum_f(g);
  const float gold = g + startt[tg(0)] + endt[tg(len - 1)];

  float Ecol[CT];
#pragma unroll
  for (int i = 0; i < CT; ++i) Ecol[i] = fexp(trans[i * CT + lane]);

  float alpha0 = startt[lane] + frow0[lane];
  float m0 = wave_max_f(alpha0);
  float M = m0;
  float aj = fexp(alpha0 - m0);
  a_sh[lane] = aj;

  float fcur = frow0[CT + lane];
  float fnext = frow0[2 * CT + lane];
  for (int s = 1; s < len; ++s) {
    float ef = fexp(fcur);
    fcur = fnext;
    int sp = s + 2;
    sp = sp < CS ? sp : CS - 1;
    fnext = frow0[(size_t)sp * CT + lane];

    float acc0 = 0.f, acc1 = 0.f, acc2 = 0.f, acc3 = 0.f;
#pragma unroll
    for (int i = 0; i < CT; i += 4) {
      float4 av = *(const float4*)(&a_sh[i]);
      acc0 = fmaf(av.x, Ecol[i + 0], acc0);
      acc1 = fmaf(av.y, Ecol[i + 1], acc1);
      acc2 = fmaf(av.z, Ecol[i + 2], acc2);
      acc3 = fmaf(av.w, Ecol[i + 3], acc3);
    }
    float v = ((acc0 + acc1) + (acc2 + acc3)) * ef;
    if ((s & 3) == 0) {
      float cmx = wave_max_f(v);
      M += flog(cmx);
      v = v * __builtin_amdgcn_rcpf(cmx);
    }
    aj = v;
    a_sh[lane] = aj;
  }
  float se = wave_sum_f(aj * fexp(endt[lane]));
  float fwd = M + flog(se);
  if (lane == 0) atomicAdd(out, fwd - gold);
}

extern "C" void kernel_launch(void* const* d_in, const int* in_sizes, int n_in,
                              void* d_out, int out_size, void* d_ws, size_t ws_size,
                              hipStream_t stream) {
  const float* feats = (const float*)d_in[0];
  const float* trans = (const float*)d_in[1];
  const float* startt = (const float*)d_in[2];
  const float* endt = (const float*)d_in[3];
  const int* tags = (const int*)d_in[4];
  const unsigned char* mask = (const unsigned char*)d_in[5];
  float* out = (float*)d_out;

  int Bn = in_sizes[5] / CS;
  size_t qbytes = (size_t)Bn * NCH * 4096 * 2;  // u16 Q matrices
  size_t need = qbytes + (size_t)Bn * NCH * 4;

  hipMemsetAsync(out, 0, sizeof(float) * out_size, stream);
  if (ws_size >= need) {
    unsigned short* qws = (unsigned short*)d_ws;
    float* scalews = (float*)((char*)d_ws + qbytes);
    crf_chunkA<<<Bn * NCH, 64, 0, stream>>>(feats, trans, mask, qws, scalews);
    crf_phaseB<<<Bn, 64, 0, stream>>>(feats, trans, startt, endt, tags, mask, qws, scalews, out);
  } else {
    crf_nll_kernel<<<Bn, 64, 0, stream>>>(feats, trans, startt, endt, tags, mask, out);
  }
}